// Round 3
// baseline (2319.603 us; speedup 1.0000x reference)
//
#include <hip/hip_runtime.h>
#include <hip/hip_bf16.h>
#include <cstdint>
#include <cstddef>

__device__ __forceinline__ float rl_f(float v, int lane) {
  return __int_as_float(__builtin_amdgcn_readlane(__float_as_int(v), lane));
}

// One LSTM layer, rows (= gate pre-activations, 4H of them) mapped 1:1 to threads.
// Block = 4H threads (NW waves), grid = 512 (one block per batch chain).
// Row r: weights Wih[r][:], Whh[r][:] live in VGPRs. x_t is wave-uniform ->
// scalar loads (SGPRs). h_{t-1}: every wave maintains c/h redundantly in lane
// k (<H), broadcast via v_readlane -> SGPR operand of v_fma (no LDS).
// Only cross-wave traffic: activated gates through padded LDS, ping-pong
// buffered -> ONE barrier per timestep.
// IN_MODE:  0 = f32 seq [B,T,D], 1 = bf16 seq, 2 = f32 latent [B,D] (folded into bias)
// OUT_MODE: 0 = f32 seq [B,T,H], 1 = bf16 seq, 2 = f32 last-h [B,H]
template <int D, int H, int NW, int IN_MODE, int OUT_MODE>
__launch_bounds__(NW * 64, 2)
__global__ void lstm_rl(const float* __restrict__ Wih, const float* __restrict__ Whh,
                        const float* __restrict__ bih, const float* __restrict__ bhh,
                        const void* __restrict__ inp, void* __restrict__ outp, int T) {
  static_assert(NW * 64 == 4 * H, "rows must equal threads");
  __shared__ float gbuf[2][H * 5 + 4];  // stride-5 padding: conflict-free b32

  const int tid = threadIdx.x;  // row r = tid
  const int b   = blockIdx.x;
  const int g   = tid / H;      // gate type 0..3 = i,f,g,o
  const int u   = tid - g * H;  // hidden unit of this row
  const int l   = tid & 63;     // lane

  float whh[H];
  {
    const float* wr = Whh + (size_t)tid * H;
#pragma unroll
    for (int j = 0; j < H / 4; ++j) {
      float4 q = ((const float4*)wr)[j];
      whh[4 * j + 0] = q.x; whh[4 * j + 1] = q.y;
      whh[4 * j + 2] = q.z; whh[4 * j + 3] = q.w;
    }
  }
  float base = bih[tid] + bhh[tid];
  float wih[(IN_MODE == 2) ? 1 : D];
  if (IN_MODE != 2) {
    const float* wr = Wih + (size_t)tid * D;
#pragma unroll
    for (int j = 0; j < D / 4; ++j) {
      float4 q = ((const float4*)wr)[j];
      wih[4 * j + 0] = q.x; wih[4 * j + 1] = q.y;
      wih[4 * j + 2] = q.z; wih[4 * j + 3] = q.w;
    }
  } else {
    const float* wr  = Wih + (size_t)tid * D;
    const float* lat = (const float*)inp + (size_t)b * D;  // uniform reads
#pragma unroll
    for (int j = 0; j < D; ++j) base = fmaf(wr[j], lat[j], base);
  }

  // Branch-free activation: sigma(x) = 1/(1+exp2(-1.4427x)); tanh(x) = 2*sigma(2x)-1.
  const bool isT = (g == 2);
  const float sA = isT ? -2.88539008f : -1.44269504f;
  const float aA = isT ? 2.f : 1.f;
  const float bA = isT ? -1.f : 0.f;

  float cc = 0.f, hreg = 0.f;
  int p = 0;
  for (int t = 0; t < T; ++t) {
    // ---- x_t: wave-uniform -> scalar loads, issued early, consumed late
    float xs[(IN_MODE == 2) ? 1 : D];
    if (IN_MODE == 0) {
      const float* xr = (const float*)inp + ((size_t)b * T + t) * D;
#pragma unroll
      for (int d = 0; d < D; ++d) xs[d] = xr[d];
    } else if (IN_MODE == 1) {
      const uint32_t* xr = (const uint32_t*)inp + (((size_t)b * T + t) * D) / 2;
#pragma unroll
      for (int d2 = 0; d2 < D / 2; ++d2) {
        uint32_t v = xr[d2];
        xs[2 * d2 + 0] = __uint_as_float(v << 16);
        xs[2 * d2 + 1] = __uint_as_float(v & 0xffff0000u);
      }
    }
    // ---- h-part: readlane broadcast, 4-way interleaved accumulators
    float a0 = base, a1 = 0.f, a2 = 0.f, a3 = 0.f;
#pragma unroll
    for (int j = 0; j < H; j += 4) {
      a0 = fmaf(whh[j + 0], rl_f(hreg, j + 0), a0);
      a1 = fmaf(whh[j + 1], rl_f(hreg, j + 1), a1);
      a2 = fmaf(whh[j + 2], rl_f(hreg, j + 2), a2);
      a3 = fmaf(whh[j + 3], rl_f(hreg, j + 3), a3);
    }
    // ---- x-part: SGPR operand FMAs
    if (IN_MODE != 2) {
#pragma unroll
      for (int d = 0; d < D; d += 4) {
        a0 = fmaf(wih[d + 0], xs[d + 0], a0);
        a1 = fmaf(wih[d + 1], xs[d + 1], a1);
        a2 = fmaf(wih[d + 2], xs[d + 2], a2);
        a3 = fmaf(wih[d + 3], xs[d + 3], a3);
      }
    }
    float pre = (a0 + a1) + (a2 + a3);
    float e   = exp2f(sA * pre);
    float gv  = fmaf(aA, __builtin_amdgcn_rcpf(1.f + e), bA);
    gbuf[p][u * 5 + g] = gv;
    __syncthreads();  // one barrier per step (ping-pong makes WAR safe)

    if (l < H) {
      float gi = gbuf[p][l * 5 + 0];
      float gf = gbuf[p][l * 5 + 1];
      float gg = gbuf[p][l * 5 + 2];
      float go = gbuf[p][l * 5 + 3];
      cc = fmaf(gf, cc, gi * gg);
      float e2 = exp2f(-2.88539008f * cc);
      float th = fmaf(2.f, __builtin_amdgcn_rcpf(1.f + e2), -1.f);
      hreg = go * th;
      if (OUT_MODE == 0) {
        if (tid < H) ((float*)outp)[((size_t)b * T + t) * H + tid] = hreg;
      } else if (OUT_MODE == 1) {
        if (tid < H) ((__hip_bfloat16*)outp)[((size_t)b * T + t) * H + tid] = __float2bfloat16(hreg);
      } else {
        if (tid < H && t == T - 1) ((float*)outp)[(size_t)b * H + tid] = hreg;
      }
    }
    p ^= 1;
  }
}

extern "C" void kernel_launch(void* const* d_in, const int* in_sizes, int n_in,
                              void* d_out, int out_size, void* d_ws, size_t ws_size,
                              hipStream_t stream) {
  (void)in_sizes; (void)n_in; (void)out_size;
  const float* x = (const float*)d_in[0];
  const float *W[6], *U[6], *Bi[6], *Bh[6];
  for (int lyr = 0; lyr < 6; ++lyr) {
    W[lyr]  = (const float*)d_in[1 + 4 * lyr + 0];
    U[lyr]  = (const float*)d_in[1 + 4 * lyr + 1];
    Bi[lyr] = (const float*)d_in[1 + 4 * lyr + 2];
    Bh[lyr] = (const float*)d_in[1 + 4 * lyr + 3];
  }
  float* out = (float*)d_out;
  const int T = 512;
  dim3 grid(512);

  const size_t szA32 = (size_t)512 * 512 * 48 * 4;  // 50.3 MB
  const size_t szB32 = (size_t)512 * 512 * 32 * 4;  // 33.6 MB
  const size_t szLat = (size_t)512 * 16 * 4;
  char* ws = (char*)d_ws;

  if (ws_size >= szA32 + szB32 + szLat) {
    float* A   = (float*)ws;
    float* Bf  = (float*)(ws + szA32);
    float* lat = (float*)(ws + szA32 + szB32);
    lstm_rl<64, 48, 3, 0, 0><<<grid, 192, 0, stream>>>(W[0], U[0], Bi[0], Bh[0], x,   A,   T);
    lstm_rl<48, 32, 2, 0, 0><<<grid, 128, 0, stream>>>(W[1], U[1], Bi[1], Bh[1], A,   Bf,  T);
    lstm_rl<32, 16, 1, 0, 2><<<grid,  64, 0, stream>>>(W[2], U[2], Bi[2], Bh[2], Bf,  lat, T);
    lstm_rl<16, 32, 2, 2, 0><<<grid, 128, 0, stream>>>(W[3], U[3], Bi[3], Bh[3], lat, Bf,  T);
    lstm_rl<32, 48, 3, 0, 0><<<grid, 192, 0, stream>>>(W[4], U[4], Bi[4], Bh[4], Bf,  A,   T);
    lstm_rl<48, 64, 4, 0, 0><<<grid, 256, 0, stream>>>(W[5], U[5], Bi[5], Bh[5], A,   out, T);
  } else {
    const size_t szA16 = szA32 / 2, szB16 = szB32 / 2;
    __hip_bfloat16* A  = (__hip_bfloat16*)ws;
    __hip_bfloat16* Bf = (__hip_bfloat16*)(ws + szA16);
    float* lat = (float*)(ws + szA16 + szB16);
    lstm_rl<64, 48, 3, 0, 1><<<grid, 192, 0, stream>>>(W[0], U[0], Bi[0], Bh[0], x,   A,   T);
    lstm_rl<48, 32, 2, 1, 1><<<grid, 128, 0, stream>>>(W[1], U[1], Bi[1], Bh[1], A,   Bf,  T);
    lstm_rl<32, 16, 1, 1, 2><<<grid,  64, 0, stream>>>(W[2], U[2], Bi[2], Bh[2], Bf,  lat, T);
    lstm_rl<16, 32, 2, 2, 1><<<grid, 128, 0, stream>>>(W[3], U[3], Bi[3], Bh[3], lat, Bf,  T);
    lstm_rl<32, 48, 3, 1, 1><<<grid, 192, 0, stream>>>(W[4], U[4], Bi[4], Bh[4], Bf,  A,   T);
    lstm_rl<48, 64, 4, 1, 0><<<grid, 256, 0, stream>>>(W[5], U[5], Bi[5], Bh[5], A,   out, T);
  }
}